// Round 7
// baseline (359.793 us; speedup 1.0000x reference)
//
#include <hip/hip_runtime.h>

// ---------------------------------------------------------------------------
// HFLongFormerSelfAttentionBlock — MI355X implementation (round 7)
//
// I/O fp32; internal bf16 MFMA, fp32 accumulation/epilogues.
// Round-7: gemm64_bt BK=128 (half the barriers, same XOR swizzle, 32 KB LDS
// keeps 4 blocks/CU), all 4 preprocessing dispatches merged into one flat
// `prep` kernel, attn launch_bounds (256,3) to allow 3 blocks/CU.
// ---------------------------------------------------------------------------

using bf16x8 = __attribute__((ext_vector_type(8))) short;
using bf16x4 = __attribute__((ext_vector_type(4))) short;
using f32x4  = __attribute__((ext_vector_type(4))) float;

__device__ __forceinline__ float b2f(short s) {
    return __uint_as_float(((unsigned int)(unsigned short)s) << 16);
}
__device__ __forceinline__ short f2b(float f) {
    unsigned int u = __float_as_uint(f);
    u += 0x7fffu + ((u >> 16) & 1u);   // round-to-nearest-even
    return (short)(u >> 16);
}
__device__ __forceinline__ f32x4 mfma16(bf16x8 a, bf16x8 b, f32x4 c) {
    return __builtin_amdgcn_mfma_f32_16x16x32_bf16(a, b, c, 0, 0, 0);
}
__device__ __forceinline__ float safe_exp(float x) {
    return expf((x <= 0.f) ? x : 0.f);
}
// async global->LDS, 16 B per lane; LDS dest = wave-uniform base + lane*16
__device__ __forceinline__ void load_lds16(const short* g, short* l) {
    __builtin_amdgcn_global_load_lds((const __attribute__((address_space(1))) void*)g,
                                     (__attribute__((address_space(3))) void*)l, 16, 0, 0);
}
#define NEGF (-3.0e38f)

// ---------------------------------------------------------------------------
// prep: one dispatch does wq/wk/wv transpose, w1/w2 transpose, x fp32->bf16.
// flat grid 15360 x 256 threads.
//   [0, 3072)      wqkv transpose (3 x 32x32-tile grids)
//   [3072, 7168)   w1 transpose  (in 1024x4096, grid 128x32)
//   [7168, 11264)  w2 transpose  (in 4096x1024, grid 32x128)
//   [11264, 15360) x convert     (4096 blocks x 1024 elems)
// ---------------------------------------------------------------------------
__device__ __forceinline__ void transpose_body(
    const float* __restrict__ in, short* __restrict__ out,
    int R, int C, int bx, int by, int t, short (*tile)[33])
{
    int tx = t & 31, ty = t >> 5;
    for (int i = ty; i < 32; i += 8)
        tile[i][tx] = f2b(in[(size_t)(by + i) * C + bx + tx]);
    __syncthreads();
    for (int i = ty; i < 32; i += 8)
        out[(size_t)(bx + i) * R + by + tx] = tile[tx][i];
}

__global__ __launch_bounds__(256) void prep(
    const float* __restrict__ wq, const float* __restrict__ wk,
    const float* __restrict__ wv, const float* __restrict__ w1,
    const float* __restrict__ w2, const float* __restrict__ x,
    short* __restrict__ wqkvt, short* __restrict__ w1t,
    short* __restrict__ w2t, short* __restrict__ xb)
{
    __shared__ short tile[32][33];
    int bid = blockIdx.x, t = threadIdx.x;
    if (bid < 3072) {
        int z = bid >> 10, r = bid & 1023;
        const float* in = (z == 0) ? wq : (z == 1) ? wk : wv;
        transpose_body(in, wqkvt + (size_t)z * 1048576, 1024, 1024,
                       (r & 31) * 32, (r >> 5) * 32, t, tile);
    } else if (bid < 7168) {
        int r = bid - 3072;
        transpose_body(w1, w1t, 1024, 4096, (r & 127) * 32, (r >> 7) * 32, t, tile);
    } else if (bid < 11264) {
        int r = bid - 7168;
        transpose_body(w2, w2t, 4096, 1024, (r & 31) * 32, (r >> 5) * 32, t, tile);
    } else {
        int r = bid - 11264;
        int i = (r * 256 + t) * 4;
        f32x4 v = *(const f32x4*)(x + i);
        bf16x4 o;
#pragma unroll
        for (int j = 0; j < 4; ++j) o[j] = f2b(v[j]);
        *(bf16x4*)(xb + i) = o;
    }
}

// ---------------------------------------------------------------------------
// GEMM 128x128, BK=64, XOR-swizzled LDS k-chunks.
// LDS layout: L[row][slot] = G[row][slot ^ (row&7)]  (slot/chunk = 8 shorts).
// mode 0: QKV — bias bq/bk/bv by col segment, Q scaled, V written to Vt(b,h,d,s)
// mode 1: C = bf16(gelu(acc + bias0[col]))
// ---------------------------------------------------------------------------
__global__ __launch_bounds__(256, 3) void gemm_bt(
    const short* __restrict__ A, const short* __restrict__ Bt,
    const float* __restrict__ bias0, const float* __restrict__ bias1,
    const float* __restrict__ bias2,
    short* __restrict__ C, short* __restrict__ Vt,
    int M, int N, int K, float scale, int mode)
{
    __shared__ short As[128 * 64];
    __shared__ short Bs[128 * 64];
    int m0 = blockIdx.x * 128, n0 = blockIdx.y * 128;
    int t = threadIdx.x;
    int wave = t >> 6, lane = t & 63, quad = lane >> 4, l16 = lane & 15;
    int wr = (wave >> 1) * 64, wc = (wave & 1) * 64;

    const short* ap[4]; const short* bp[4]; short* la[4]; short* lb[4];
    int gk = (((lane & 7) ^ (lane >> 3)) * 8);
#pragma unroll
    for (int l = 0; l < 4; ++l) {
        int c = wave * 4 + l;
        int row = c * 8 + (lane >> 3);
        ap[l] = A  + (size_t)(m0 + row) * K + gk;
        bp[l] = Bt + (size_t)(n0 + row) * K + gk;
        la[l] = As + c * 512;
        lb[l] = Bs + c * 512;
    }
    int sw = l16 & 7;   // frag-read swizzle key

    f32x4 acc[4][4] = {};
    for (int k0 = 0; k0 < K; k0 += 64) {
#pragma unroll
        for (int l = 0; l < 4; ++l) { load_lds16(ap[l] + k0, la[l]); load_lds16(bp[l] + k0, lb[l]); }
        __syncthreads();
#pragma unroll
        for (int ks = 0; ks < 2; ++ks) {
            int slot = ((ks * 4 + quad) ^ sw) * 8;
            bf16x8 af[4], bfr[4];
#pragma unroll
            for (int i = 0; i < 4; ++i)
                af[i] = *(bf16x8*)(As + (wr + i * 16 + l16) * 64 + slot);
#pragma unroll
            for (int j = 0; j < 4; ++j)
                bfr[j] = *(bf16x8*)(Bs + (wc + j * 16 + l16) * 64 + slot);
#pragma unroll
            for (int i = 0; i < 4; ++i)
#pragma unroll
                for (int j = 0; j < 4; ++j)
                    acc[i][j] = mfma16(af[i], bfr[j], acc[i][j]);
        }
        __syncthreads();
    }

#pragma unroll
    for (int j = 0; j < 4; ++j) {
        int col = n0 + wc + j * 16 + l16;
        if (mode == 1) {
            float bs = bias0[col];
#pragma unroll
            for (int i = 0; i < 4; ++i) {
#pragma unroll
                for (int r = 0; r < 4; ++r) {
                    int row = m0 + wr + i * 16 + quad * 4 + r;
                    float v = acc[i][j][r] + bs;
                    v = 0.5f * v * (1.0f + erff(v * 0.70710678118f));
                    C[(size_t)row * N + col] = f2b(v);
                }
            }
        } else {
            int seg = col >> 10;
            const float* bpt = (seg == 0) ? bias0 : (seg == 1) ? bias1 : bias2;
            float bs = bpt[col & 1023];
            if (seg < 2) {
                float sc = (seg == 0) ? scale : 1.0f;
#pragma unroll
                for (int i = 0; i < 4; ++i)
#pragma unroll
                    for (int r = 0; r < 4; ++r) {
                        int row = m0 + wr + i * 16 + quad * 4 + r;
                        C[(size_t)row * N + col] = f2b((acc[i][j][r] + bs) * sc);
                    }
            } else {
                // V part -> Vt (b, h, d, s), 4 consecutive s per thread
                int h = (col >> 6) & 15, d = col & 63;
#pragma unroll
                for (int i = 0; i < 4; ++i) {
                    int row0 = m0 + wr + i * 16 + quad * 4;
                    int bb = row0 >> 11, s0 = row0 & 2047;
                    bf16x4 vv;
#pragma unroll
                    for (int r = 0; r < 4; ++r) vv[r] = f2b(acc[i][j][r] + bs);
                    *(bf16x4*)(Vt + (((size_t)(bb * 16 + h)) * 64 + d) * 2048 + s0) = vv;
                }
            }
        }
    }
}

// ---------------------------------------------------------------------------
// GEMM 64x64, BK=128, XOR swizzle: Cf = A@B + bias + resf (fp32 out).
// grid (M/64, N/64); 4 waves, each a 32x32 quadrant. LDS 2 x 16 KB ->
// 4 blocks/CU. 32 K-steps at K=4096 (half the barriers of BK=64).
// ---------------------------------------------------------------------------
__global__ __launch_bounds__(256, 4) void gemm64_bt(
    const short* __restrict__ A, const short* __restrict__ Bt,
    const float* __restrict__ bias, const float* __restrict__ resf,
    float* __restrict__ Cf, int M, int N, int K)
{
    __shared__ short As[64 * 128];
    __shared__ short Bs[64 * 128];
    int m0 = blockIdx.x * 64, n0 = blockIdx.y * 64;
    int t = threadIdx.x;
    int wave = t >> 6, lane = t & 63, quad = lane >> 4, l16 = lane & 15;
    int wr = (wave >> 1) * 32, wc = (wave & 1) * 32;

    // staging: rows are 128 shorts = 16 chunks; chunk c covers rows c*4..c*4+3.
    // lane i of chunk c: row = c*4 + (i>>4), slotpos = i&15,
    // global k-chunk = slotpos ^ (row&7).
    const short* ap[4]; const short* bp[4]; short* la[4]; short* lb[4];
#pragma unroll
    for (int l = 0; l < 4; ++l) {
        int c = wave * 4 + l;
        int row = c * 4 + (lane >> 4);
        int gk = (((lane & 15) ^ (row & 7)) * 8);
        ap[l] = A  + (size_t)(m0 + row) * K + gk;
        bp[l] = Bt + (size_t)(n0 + row) * K + gk;
        la[l] = As + c * 512;
        lb[l] = Bs + c * 512;
    }
    int sw = l16 & 7;

    f32x4 acc[2][2] = {};
    for (int k0 = 0; k0 < K; k0 += 128) {
#pragma unroll
        for (int l = 0; l < 4; ++l) { load_lds16(ap[l] + k0, la[l]); load_lds16(bp[l] + k0, lb[l]); }
        __syncthreads();
#pragma unroll
        for (int ks = 0; ks < 4; ++ks) {
            int slot = ((ks * 4 + quad) ^ sw) * 8;
            bf16x8 af[2], bfr[2];
#pragma unroll
            for (int i = 0; i < 2; ++i)
                af[i] = *(bf16x8*)(As + (wr + i * 16 + l16) * 128 + slot);
#pragma unroll
            for (int j = 0; j < 2; ++j)
                bfr[j] = *(bf16x8*)(Bs + (wc + j * 16 + l16) * 128 + slot);
#pragma unroll
            for (int i = 0; i < 2; ++i)
#pragma unroll
                for (int j = 0; j < 2; ++j)
                    acc[i][j] = mfma16(af[i], bfr[j], acc[i][j]);
        }
        __syncthreads();
    }
#pragma unroll
    for (int j = 0; j < 2; ++j) {
        int col = n0 + wc + j * 16 + l16;
        float bs = bias[col];
#pragma unroll
        for (int i = 0; i < 2; ++i) {
#pragma unroll
            for (int r = 0; r < 4; ++r) {
                int row = m0 + wr + i * 16 + quad * 4 + r;
                Cf[(size_t)row * N + col] = acc[i][j][r] + bs + resf[(size_t)row * N + col];
            }
        }
    }
}

// ---------------------------------------------------------------------------
// Windowed attention with global column (structure unchanged; launch_bounds
// raised to 3 blocks/CU — LDS 53760 B admits 3).
// ---------------------------------------------------------------------------
__global__ __launch_bounds__(256, 3) void attn_kernel(
    const short* __restrict__ QKV, const short* __restrict__ Vt,
    const int* __restrict__ mask,
    const float* __restrict__ bk, const float* __restrict__ bv,
    short* __restrict__ attn)
{
    extern __shared__ char smem[];
    short* PsQ = (short*)smem;
    short* KV  = (short*)(smem + 34816);
    float* gkf = (float*)(smem + 53248);
    float* gvf = (float*)(smem + 53504);

    int blk = blockIdx.x;
    int c = blk & 15, h = (blk >> 4) & 15, b = blk >> 8;
    int t = threadIdx.x;
    int wave = t >> 6, lane = t & 63, quad = lane >> 4, l16 = lane & 15;
    int q0 = c * 128;
    const int bs_off = b * 2048;
    const short* Q = QKV + h * 64;
    const short* K = QKV + 1024 + h * 64;

#pragma unroll
    for (int l = 0; l < 4; ++l) {
        int idx = l * 256 + t;
        int p = idx >> 3, dc = (idx & 7) * 8;
        *(bf16x8*)(PsQ + p * 72 + dc) =
            *(const bf16x8*)(Q + ((size_t)(bs_off + q0 + p)) * 3072 + dc);
    }
    if (t < 64) { gkf[t] = bk[h * 64 + t]; gvf[t] = bv[h * 64 + t]; }
    __syncthreads();

    bf16x8 aq[2][2];
#pragma unroll
    for (int ti = 0; ti < 2; ++ti)
#pragma unroll
        for (int ks = 0; ks < 2; ++ks)
            aq[ti][ks] = *(bf16x8*)(PsQ + (wave * 32 + ti * 16 + l16) * 72 + ks * 32 + quad * 8);

    float s_g[2][4];
#pragma unroll
    for (int ti = 0; ti < 2; ++ti)
#pragma unroll
        for (int r = 0; r < 4; ++r) {
            int row = wave * 32 + ti * 16 + quad * 4 + r;
            float part = 0.f;
#pragma unroll
            for (int dd = 0; dd < 4; ++dd) {
                int d = l16 * 4 + dd;
                part += b2f(PsQ[row * 72 + d]) * gkf[d];
            }
#pragma unroll
            for (int dsh = 1; dsh < 16; dsh <<= 1) part += __shfl_xor(part, dsh);
            s_g[ti][r] = part;
        }

    f32x4 o_acc[2][4] = {};
    float m_run[2][4], l_run[2][4];
#pragma unroll
    for (int ti = 0; ti < 2; ++ti)
#pragma unroll
        for (int r = 0; r < 4; ++r) { m_run[ti][r] = NEGF; l_run[ti][r] = 0.f; }

    int kt_beg = (q0 == 0) ? 1 : 0;
    int kt_end = (q0 + 256 > 2048) ? 2 : 3;
    for (int kt = kt_beg; kt < kt_end; ++kt) {
        int jb = q0 + (kt - 1) * 128;
        __syncthreads();
#pragma unroll
        for (int l = 0; l < 4; ++l) {
            int idx = l * 256 + t;
            int p = idx >> 3, dc = (idx & 7) * 8;
            *(bf16x8*)(KV + p * 72 + dc) =
                *(const bf16x8*)(K + ((size_t)(bs_off + jb + p)) * 3072 + dc);
        }
        __syncthreads();

        f32x4 s_acc[2][8] = {};
#pragma unroll
        for (int ks = 0; ks < 2; ++ks) {
            bf16x8 bk8[8];
#pragma unroll
            for (int tj = 0; tj < 8; ++tj)
                bk8[tj] = *(bf16x8*)(KV + (tj * 16 + l16) * 72 + ks * 32 + quad * 8);
#pragma unroll
            for (int ti = 0; ti < 2; ++ti)
#pragma unroll
                for (int tj = 0; tj < 8; ++tj)
                    s_acc[ti][tj] = mfma16(aq[ti][ks], bk8[tj], s_acc[ti][tj]);
        }

        float negj[8]; int jcol[8];
#pragma unroll
        for (int tj = 0; tj < 8; ++tj) {
            jcol[tj] = jb + tj * 16 + l16;
            negj[tj] = (mask[bs_off + jcol[tj]] != 0) ? NEGF : 0.f;
        }
        float tmax[2][4];
#pragma unroll
        for (int ti = 0; ti < 2; ++ti)
#pragma unroll
            for (int r = 0; r < 4; ++r) tmax[ti][r] = NEGF;
#pragma unroll
        for (int ti = 0; ti < 2; ++ti) {
            int irow_base = q0 + wave * 32 + ti * 16 + quad * 4;
#pragma unroll
            for (int tj = 0; tj < 8; ++tj)
#pragma unroll
                for (int r = 0; r < 4; ++r) {
                    int dj = jcol[tj] - (irow_base + r);
                    float sc = (dj >= -128 && dj <= 128) ? (s_acc[ti][tj][r] + negj[tj]) : NEGF;
                    s_acc[ti][tj][r] = sc;
                    tmax[ti][r] = fmaxf(tmax[ti][r], sc);
                }
        }
#pragma unroll
        for (int ti = 0; ti < 2; ++ti)
#pragma unroll
            for (int r = 0; r < 4; ++r)
#pragma unroll
                for (int dsh = 1; dsh < 16; dsh <<= 1)
                    tmax[ti][r] = fmaxf(tmax[ti][r], __shfl_xor(tmax[ti][r], dsh));

        float alpha[2][4], lsum[2][4];
#pragma unroll
        for (int ti = 0; ti < 2; ++ti)
#pragma unroll
            for (int r = 0; r < 4; ++r) {
                float mnew = fmaxf(m_run[ti][r], tmax[ti][r]);
                alpha[ti][r] = safe_exp(m_run[ti][r] - mnew);
                m_run[ti][r] = mnew;
                lsum[ti][r] = 0.f;
            }
#pragma unroll
        for (int ti = 0; ti < 2; ++ti)
#pragma unroll
            for (int tj = 0; tj < 8; ++tj)
#pragma unroll
                for (int r = 0; r < 4; ++r) {
                    float p = safe_exp(s_acc[ti][tj][r] - m_run[ti][r]);
                    lsum[ti][r] += p;
                    PsQ[(wave * 32 + ti * 16 + quad * 4 + r) * 136 + tj * 16 + l16] = f2b(p);
                }
#pragma unroll
        for (int ti = 0; ti < 2; ++ti)
#pragma unroll
            for (int r = 0; r < 4; ++r) {
#pragma unroll
                for (int dsh = 1; dsh < 16; dsh <<= 1) lsum[ti][r] += __shfl_xor(lsum[ti][r], dsh);
                l_run[ti][r] = l_run[ti][r] * alpha[ti][r] + lsum[ti][r];
            }
#pragma unroll
        for (int ti = 0; ti < 2; ++ti)
#pragma unroll
            for (int dj = 0; dj < 4; ++dj)
#pragma unroll
                for (int r = 0; r < 4; ++r) o_acc[ti][dj][r] *= alpha[ti][r];

        __syncthreads();
#pragma unroll
        for (int l = 0; l < 4; ++l) {
            int idx = l * 256 + t;
            int d = idx >> 4, kc = (idx & 15) * 8;
            *(bf16x8*)(KV + d * 136 + kc) =
                *(const bf16x8*)(Vt + ((size_t)(b * 16 + h) * 64 + d) * 2048 + jb + kc);
        }
        __syncthreads();
#pragma unroll
        for (int ks = 0; ks < 4; ++ks) {
            bf16x8 ap[2], bv8[4];
#pragma unroll
            for (int ti = 0; ti < 2; ++ti)
                ap[ti] = *(bf16x8*)(PsQ + (wave * 32 + ti * 16 + l16) * 136 + ks * 32 + quad * 8);
#pragma unroll
            for (int dj = 0; dj < 4; ++dj)
                bv8[dj] = *(bf16x8*)(KV + (dj * 16 + l16) * 136 + ks * 32 + quad * 8);
#pragma unroll
            for (int ti = 0; ti < 2; ++ti)
#pragma unroll
                for (int dj = 0; dj < 4; ++dj)
                    o_acc[ti][dj] = mfma16(ap[ti], bv8[dj], o_acc[ti][dj]);
        }
    }

#pragma unroll
    for (int ti = 0; ti < 2; ++ti) {
        int irow_base = q0 + wave * 32 + ti * 16 + quad * 4;
#pragma unroll
        for (int r = 0; r < 4; ++r) {
            int i = irow_base + r;
            float m2 = fmaxf(m_run[ti][r], s_g[ti][r]);
            float pg = safe_exp(s_g[ti][r] - m2);
            float al = safe_exp(m_run[ti][r] - m2);
            float l2 = l_run[ti][r] * al + pg;
            float invl = 1.f / fmaxf(l2, 1e-30f);
            float qm = (mask[bs_off + i] > 0) ? 0.f : 1.f;
#pragma unroll
            for (int dj = 0; dj < 4; ++dj) {
                int d = dj * 16 + l16;
                float val = (o_acc[ti][dj][r] * al + pg * gvf[d]) * invl * qm;
                attn[((size_t)(bs_off + i)) * 1024 + h * 64 + d] = f2b(val);
            }
        }
    }
}

// ---------------------------------------------------------------------------
// y = LN(x + attn) * g + b ; writes bf16 (GEMM input) AND fp32 (residual).
// ---------------------------------------------------------------------------
__global__ __launch_bounds__(256) void resid_ln(
    const float* __restrict__ x, const short* __restrict__ attn,
    const float* __restrict__ g, const float* __restrict__ be,
    short* __restrict__ yb, float* __restrict__ yf)
{
    int row = blockIdx.x, t = threadIdx.x;
    int lane = t & 63, wave = t >> 6;
    const size_t base = (size_t)row * 1024;
    float v[4]; float s = 0.f, s2 = 0.f;
#pragma unroll
    for (int i = 0; i < 4; ++i) {
        int c = i * 256 + t;
        float val = x[base + c] + b2f(attn[base + c]);
        v[i] = val; s += val; s2 += val * val;
    }
#pragma unroll
    for (int off = 32; off > 0; off >>= 1) { s += __shfl_xor(s, off); s2 += __shfl_xor(s2, off); }
    __shared__ float red[8];
    if (lane == 0) { red[wave] = s; red[4 + wave] = s2; }
    __syncthreads();
    s  = red[0] + red[1] + red[2] + red[3];
    s2 = red[4] + red[5] + red[6] + red[7];
    float mu  = s * (1.f / 1024.f);
    float var = s2 * (1.f / 1024.f) - mu * mu;
    float inv = rsqrtf(fmaxf(var, 0.f) + 1e-5f);
#pragma unroll
    for (int i = 0; i < 4; ++i) {
        int c = i * 256 + t;
        float o = (v[i] - mu) * inv * g[c] + be[c];
        yb[base + c] = f2b(o);
        yf[base + c] = o;
    }
}

// ---------------------------------------------------------------------------
// workspace layout, units = bf16 elements (2 B). total 47M units = 94 MB.
// ---------------------------------------------------------------------------
static constexpr size_t MEG      = 1048576;
static constexpr size_t OFF_WQKV = 0;            // 3M  (3072x1024 bf16)
static constexpr size_t OFF_W1T  = 3 * MEG;      // 4M
static constexpr size_t OFF_W2T  = 7 * MEG;      // 4M
static constexpr size_t OFF_XB   = 11 * MEG;     // 4M
static constexpr size_t OFF_QKV  = 15 * MEG;     // 12M (4096x3072 bf16; V third unused)
static constexpr size_t OFF_VT   = 27 * MEG;     // 4M
static constexpr size_t OFF_ATT  = 31 * MEG;     // 4M
static constexpr size_t OFF_YN   = 35 * MEG;     // 4M (bf16)
static constexpr size_t OFF_YF   = 39 * MEG;     // 8M units = 4M fp32
static constexpr size_t OFF_H    = OFF_QKV;      // 16M, aliases QKV+VT (dead)

extern "C" void kernel_launch(void* const* d_in, const int* in_sizes, int n_in,
                              void* d_out, int out_size, void* d_ws, size_t ws_size,
                              hipStream_t stream) {
    (void)in_sizes; (void)n_in; (void)out_size; (void)ws_size;
    const float* x    = (const float*)d_in[0];
    const int*   mask = (const int*)  d_in[1];
    const float* wq   = (const float*)d_in[2];
    const float* bq   = (const float*)d_in[3];
    const float* wk   = (const float*)d_in[4];
    const float* bk   = (const float*)d_in[5];
    const float* wv   = (const float*)d_in[6];
    const float* bv   = (const float*)d_in[7];
    // d_in[8..13] (global-query branch) are provably dead for the output
    const float* lng  = (const float*)d_in[14];
    const float* lnb  = (const float*)d_in[15];
    const float* w1   = (const float*)d_in[16];
    const float* b1   = (const float*)d_in[17];
    const float* w2   = (const float*)d_in[18];
    const float* b2   = (const float*)d_in[19];
    short* ws  = (short*)d_ws;
    float* out = (float*)d_out;

    // all preprocessing in one dispatch
    prep<<<15360, 256, 0, stream>>>(wq, wk, wv, w1, w2, x,
                                    ws + OFF_WQKV, ws + OFF_W1T,
                                    ws + OFF_W2T, ws + OFF_XB);

    // QKV = x @ [wq|wk|wv] + [bq|bk|bv]; Q scaled 1/8; V written to Vt fused
    gemm_bt<<<dim3(32, 24), 256, 0, stream>>>(ws + OFF_XB, ws + OFF_WQKV,
                                              bq, bk, bv,
                                              ws + OFF_QKV, ws + OFF_VT,
                                              4096, 3072, 1024, 0.125f, 0);

    attn_kernel<<<512, 256, 53760, stream>>>(ws + OFF_QKV, ws + OFF_VT,
                                             mask, bk, bv, ws + OFF_ATT);

    resid_ln<<<4096, 256, 0, stream>>>(x, ws + OFF_ATT, lng, lnb,
                                       ws + OFF_YN, (float*)(ws + OFF_YF));

    // h = gelu(y@w1 + b1)
    gemm_bt<<<dim3(32, 32), 256, 0, stream>>>(ws + OFF_YN, ws + OFF_W1T,
                                              b1, nullptr, nullptr,
                                              ws + OFF_H, nullptr,
                                              4096, 4096, 1024, 1.0f, 1);
    // out = y + h@w2 + b2  (64x64 tiles, BK=128)
    gemm64_bt<<<dim3(64, 16), 256, 0, stream>>>(ws + OFF_H, ws + OFF_W2T,
                                                b2, (const float*)(ws + OFF_YF),
                                                out, 4096, 1024, 4096);
}

// Round 8
// 339.660 us; speedup vs baseline: 1.0593x; 1.0593x over previous
//
#include <hip/hip_runtime.h>

// ---------------------------------------------------------------------------
// HFLongFormerSelfAttentionBlock — MI355X implementation (round 8)
//
// I/O fp32; internal bf16 MFMA, fp32 accumulation/epilogues.
// Round-8: unique kernel names for profiling attribution (gemm_qkv /
// gemm_gelu / gemm_out64), attn reverted to launch_bounds(256,2) (the (256,3)
// cap risked VGPR spills), prep merge + gemm_out64 BK=128 kept.
// ---------------------------------------------------------------------------

using bf16x8 = __attribute__((ext_vector_type(8))) short;
using bf16x4 = __attribute__((ext_vector_type(4))) short;
using f32x4  = __attribute__((ext_vector_type(4))) float;

__device__ __forceinline__ float b2f(short s) {
    return __uint_as_float(((unsigned int)(unsigned short)s) << 16);
}
__device__ __forceinline__ short f2b(float f) {
    unsigned int u = __float_as_uint(f);
    u += 0x7fffu + ((u >> 16) & 1u);   // round-to-nearest-even
    return (short)(u >> 16);
}
__device__ __forceinline__ f32x4 mfma16(bf16x8 a, bf16x8 b, f32x4 c) {
    return __builtin_amdgcn_mfma_f32_16x16x32_bf16(a, b, c, 0, 0, 0);
}
__device__ __forceinline__ float safe_exp(float x) {
    return expf((x <= 0.f) ? x : 0.f);
}
// async global->LDS, 16 B per lane; LDS dest = wave-uniform base + lane*16
__device__ __forceinline__ void load_lds16(const short* g, short* l) {
    __builtin_amdgcn_global_load_lds((const __attribute__((address_space(1))) void*)g,
                                     (__attribute__((address_space(3))) void*)l, 16, 0, 0);
}
#define NEGF (-3.0e38f)

// ---------------------------------------------------------------------------
// prep: one dispatch: wq/wk/wv transpose, w1/w2 transpose, x fp32->bf16.
// ---------------------------------------------------------------------------
__device__ __forceinline__ void transpose_body(
    const float* __restrict__ in, short* __restrict__ out,
    int R, int C, int bx, int by, int t, short (*tile)[33])
{
    int tx = t & 31, ty = t >> 5;
    for (int i = ty; i < 32; i += 8)
        tile[i][tx] = f2b(in[(size_t)(by + i) * C + bx + tx]);
    __syncthreads();
    for (int i = ty; i < 32; i += 8)
        out[(size_t)(bx + i) * R + by + tx] = tile[tx][i];
}

__global__ __launch_bounds__(256) void prep(
    const float* __restrict__ wq, const float* __restrict__ wk,
    const float* __restrict__ wv, const float* __restrict__ w1,
    const float* __restrict__ w2, const float* __restrict__ x,
    short* __restrict__ wqkvt, short* __restrict__ w1t,
    short* __restrict__ w2t, short* __restrict__ xb)
{
    __shared__ short tile[32][33];
    int bid = blockIdx.x, t = threadIdx.x;
    if (bid < 3072) {
        int z = bid >> 10, r = bid & 1023;
        const float* in = (z == 0) ? wq : (z == 1) ? wk : wv;
        transpose_body(in, wqkvt + (size_t)z * 1048576, 1024, 1024,
                       (r & 31) * 32, (r >> 5) * 32, t, tile);
    } else if (bid < 7168) {
        int r = bid - 3072;
        transpose_body(w1, w1t, 1024, 4096, (r & 127) * 32, (r >> 7) * 32, t, tile);
    } else if (bid < 11264) {
        int r = bid - 7168;
        transpose_body(w2, w2t, 4096, 1024, (r & 31) * 32, (r >> 5) * 32, t, tile);
    } else {
        int r = bid - 11264;
        int i = (r * 256 + t) * 4;
        f32x4 v = *(const f32x4*)(x + i);
        bf16x4 o;
#pragma unroll
        for (int j = 0; j < 4; ++j) o[j] = f2b(v[j]);
        *(bf16x4*)(xb + i) = o;
    }
}

// ---------------------------------------------------------------------------
// Shared 128x128 BK=64 main loop (XOR-swizzled LDS), used by both GEMMs.
// ---------------------------------------------------------------------------
__device__ __forceinline__ void gemm128_core(
    const short* __restrict__ A, const short* __restrict__ Bt,
    short* As, short* Bs, int m0, int n0, int K,
    int wave, int lane, int quad, int l16, int wr, int wc,
    f32x4 (&acc)[4][4])
{
    const short* ap[4]; const short* bp[4]; short* la[4]; short* lb[4];
    int gk = (((lane & 7) ^ (lane >> 3)) * 8);
#pragma unroll
    for (int l = 0; l < 4; ++l) {
        int c = wave * 4 + l;
        int row = c * 8 + (lane >> 3);
        ap[l] = A  + (size_t)(m0 + row) * K + gk;
        bp[l] = Bt + (size_t)(n0 + row) * K + gk;
        la[l] = As + c * 512;
        lb[l] = Bs + c * 512;
    }
    int sw = l16 & 7;
    for (int k0 = 0; k0 < K; k0 += 64) {
#pragma unroll
        for (int l = 0; l < 4; ++l) { load_lds16(ap[l] + k0, la[l]); load_lds16(bp[l] + k0, lb[l]); }
        __syncthreads();
#pragma unroll
        for (int ks = 0; ks < 2; ++ks) {
            int slot = ((ks * 4 + quad) ^ sw) * 8;
            bf16x8 af[4], bfr[4];
#pragma unroll
            for (int i = 0; i < 4; ++i)
                af[i] = *(bf16x8*)(As + (wr + i * 16 + l16) * 64 + slot);
#pragma unroll
            for (int j = 0; j < 4; ++j)
                bfr[j] = *(bf16x8*)(Bs + (wc + j * 16 + l16) * 64 + slot);
#pragma unroll
            for (int i = 0; i < 4; ++i)
#pragma unroll
                for (int j = 0; j < 4; ++j)
                    acc[i][j] = mfma16(af[i], bfr[j], acc[i][j]);
        }
        __syncthreads();
    }
}

// QKV GEMM: M=4096, N=3072, K=1024. Q scaled 1/8, V -> Vt(b,h,d,s).
__global__ __launch_bounds__(256, 3) void gemm_qkv(
    const short* __restrict__ A, const short* __restrict__ Bt,
    const float* __restrict__ bq, const float* __restrict__ bk,
    const float* __restrict__ bv,
    short* __restrict__ C, short* __restrict__ Vt)
{
    __shared__ short As[128 * 64];
    __shared__ short Bs[128 * 64];
    const int N = 3072, K = 1024;
    int m0 = blockIdx.x * 128, n0 = blockIdx.y * 128;
    int t = threadIdx.x;
    int wave = t >> 6, lane = t & 63, quad = lane >> 4, l16 = lane & 15;
    int wr = (wave >> 1) * 64, wc = (wave & 1) * 64;
    f32x4 acc[4][4] = {};
    gemm128_core(A, Bt, As, Bs, m0, n0, K, wave, lane, quad, l16, wr, wc, acc);

#pragma unroll
    for (int j = 0; j < 4; ++j) {
        int col = n0 + wc + j * 16 + l16;
        int seg = col >> 10;
        const float* bpt = (seg == 0) ? bq : (seg == 1) ? bk : bv;
        float bs = bpt[col & 1023];
        if (seg < 2) {
            float sc = (seg == 0) ? 0.125f : 1.0f;
#pragma unroll
            for (int i = 0; i < 4; ++i)
#pragma unroll
                for (int r = 0; r < 4; ++r) {
                    int row = m0 + wr + i * 16 + quad * 4 + r;
                    C[(size_t)row * N + col] = f2b((acc[i][j][r] + bs) * sc);
                }
        } else {
            int h = (col >> 6) & 15, d = col & 63;
#pragma unroll
            for (int i = 0; i < 4; ++i) {
                int row0 = m0 + wr + i * 16 + quad * 4;
                int bb = row0 >> 11, s0 = row0 & 2047;
                bf16x4 vv;
#pragma unroll
                for (int r = 0; r < 4; ++r) vv[r] = f2b(acc[i][j][r] + bs);
                *(bf16x4*)(Vt + (((size_t)(bb * 16 + h)) * 64 + d) * 2048 + s0) = vv;
            }
        }
    }
}

// MLP1 GEMM: M=4096, N=4096, K=1024, gelu epilogue.
__global__ __launch_bounds__(256, 3) void gemm_gelu(
    const short* __restrict__ A, const short* __restrict__ Bt,
    const float* __restrict__ bias, short* __restrict__ C)
{
    __shared__ short As[128 * 64];
    __shared__ short Bs[128 * 64];
    const int N = 4096, K = 1024;
    int m0 = blockIdx.x * 128, n0 = blockIdx.y * 128;
    int t = threadIdx.x;
    int wave = t >> 6, lane = t & 63, quad = lane >> 4, l16 = lane & 15;
    int wr = (wave >> 1) * 64, wc = (wave & 1) * 64;
    f32x4 acc[4][4] = {};
    gemm128_core(A, Bt, As, Bs, m0, n0, K, wave, lane, quad, l16, wr, wc, acc);

#pragma unroll
    for (int j = 0; j < 4; ++j) {
        int col = n0 + wc + j * 16 + l16;
        float bs = bias[col];
#pragma unroll
        for (int i = 0; i < 4; ++i) {
#pragma unroll
            for (int r = 0; r < 4; ++r) {
                int row = m0 + wr + i * 16 + quad * 4 + r;
                float v = acc[i][j][r] + bs;
                v = 0.5f * v * (1.0f + erff(v * 0.70710678118f));
                C[(size_t)row * N + col] = f2b(v);
            }
        }
    }
}

// ---------------------------------------------------------------------------
// MLP2 GEMM 64x64, BK=128, XOR swizzle: Cf = A@B + bias + resf (fp32 out).
// grid (64,16) = 1024 blocks; LDS 2x16 KB -> 4 blocks/CU; 32 K-steps.
// ---------------------------------------------------------------------------
__global__ __launch_bounds__(256, 4) void gemm_out64(
    const short* __restrict__ A, const short* __restrict__ Bt,
    const float* __restrict__ bias, const float* __restrict__ resf,
    float* __restrict__ Cf, int M, int N, int K)
{
    __shared__ short As[64 * 128];
    __shared__ short Bs[64 * 128];
    int m0 = blockIdx.x * 64, n0 = blockIdx.y * 64;
    int t = threadIdx.x;
    int wave = t >> 6, lane = t & 63, quad = lane >> 4, l16 = lane & 15;
    int wr = (wave >> 1) * 32, wc = (wave & 1) * 32;

    const short* ap[4]; const short* bp[4]; short* la[4]; short* lb[4];
#pragma unroll
    for (int l = 0; l < 4; ++l) {
        int c = wave * 4 + l;
        int row = c * 4 + (lane >> 4);
        int gk = (((lane & 15) ^ (row & 7)) * 8);
        ap[l] = A  + (size_t)(m0 + row) * K + gk;
        bp[l] = Bt + (size_t)(n0 + row) * K + gk;
        la[l] = As + c * 512;
        lb[l] = Bs + c * 512;
    }
    int sw = l16 & 7;

    f32x4 acc[2][2] = {};
    for (int k0 = 0; k0 < K; k0 += 128) {
#pragma unroll
        for (int l = 0; l < 4; ++l) { load_lds16(ap[l] + k0, la[l]); load_lds16(bp[l] + k0, lb[l]); }
        __syncthreads();
#pragma unroll
        for (int ks = 0; ks < 4; ++ks) {
            int slot = ((ks * 4 + quad) ^ sw) * 8;
            bf16x8 af[2], bfr[2];
#pragma unroll
            for (int i = 0; i < 2; ++i)
                af[i] = *(bf16x8*)(As + (wr + i * 16 + l16) * 128 + slot);
#pragma unroll
            for (int j = 0; j < 2; ++j)
                bfr[j] = *(bf16x8*)(Bs + (wc + j * 16 + l16) * 128 + slot);
#pragma unroll
            for (int i = 0; i < 2; ++i)
#pragma unroll
                for (int j = 0; j < 2; ++j)
                    acc[i][j] = mfma16(af[i], bfr[j], acc[i][j]);
        }
        __syncthreads();
    }
#pragma unroll
    for (int j = 0; j < 2; ++j) {
        int col = n0 + wc + j * 16 + l16;
        float bs = bias[col];
#pragma unroll
        for (int i = 0; i < 2; ++i) {
#pragma unroll
            for (int r = 0; r < 4; ++r) {
                int row = m0 + wr + i * 16 + quad * 4 + r;
                Cf[(size_t)row * N + col] = acc[i][j][r] + bs + resf[(size_t)row * N + col];
            }
        }
    }
}

// ---------------------------------------------------------------------------
// Windowed attention with global column (r6 version, launch_bounds (256,2)).
// ---------------------------------------------------------------------------
__global__ __launch_bounds__(256, 2) void attn_kernel(
    const short* __restrict__ QKV, const short* __restrict__ Vt,
    const int* __restrict__ mask,
    const float* __restrict__ bk, const float* __restrict__ bv,
    short* __restrict__ attn)
{
    extern __shared__ char smem[];
    short* PsQ = (short*)smem;
    short* KV  = (short*)(smem + 34816);
    float* gkf = (float*)(smem + 53248);
    float* gvf = (float*)(smem + 53504);

    int blk = blockIdx.x;
    int c = blk & 15, h = (blk >> 4) & 15, b = blk >> 8;
    int t = threadIdx.x;
    int wave = t >> 6, lane = t & 63, quad = lane >> 4, l16 = lane & 15;
    int q0 = c * 128;
    const int bs_off = b * 2048;
    const short* Q = QKV + h * 64;
    const short* K = QKV + 1024 + h * 64;

#pragma unroll
    for (int l = 0; l < 4; ++l) {
        int idx = l * 256 + t;
        int p = idx >> 3, dc = (idx & 7) * 8;
        *(bf16x8*)(PsQ + p * 72 + dc) =
            *(const bf16x8*)(Q + ((size_t)(bs_off + q0 + p)) * 3072 + dc);
    }
    if (t < 64) { gkf[t] = bk[h * 64 + t]; gvf[t] = bv[h * 64 + t]; }
    __syncthreads();

    bf16x8 aq[2][2];
#pragma unroll
    for (int ti = 0; ti < 2; ++ti)
#pragma unroll
        for (int ks = 0; ks < 2; ++ks)
            aq[ti][ks] = *(bf16x8*)(PsQ + (wave * 32 + ti * 16 + l16) * 72 + ks * 32 + quad * 8);

    float s_g[2][4];
#pragma unroll
    for (int ti = 0; ti < 2; ++ti)
#pragma unroll
        for (int r = 0; r < 4; ++r) {
            int row = wave * 32 + ti * 16 + quad * 4 + r;
            float part = 0.f;
#pragma unroll
            for (int dd = 0; dd < 4; ++dd) {
                int d = l16 * 4 + dd;
                part += b2f(PsQ[row * 72 + d]) * gkf[d];
            }
#pragma unroll
            for (int dsh = 1; dsh < 16; dsh <<= 1) part += __shfl_xor(part, dsh);
            s_g[ti][r] = part;
        }

    f32x4 o_acc[2][4] = {};
    float m_run[2][4], l_run[2][4];
#pragma unroll
    for (int ti = 0; ti < 2; ++ti)
#pragma unroll
        for (int r = 0; r < 4; ++r) { m_run[ti][r] = NEGF; l_run[ti][r] = 0.f; }

    int kt_beg = (q0 == 0) ? 1 : 0;
    int kt_end = (q0 + 256 > 2048) ? 2 : 3;
    for (int kt = kt_beg; kt < kt_end; ++kt) {
        int jb = q0 + (kt - 1) * 128;
        __syncthreads();
#pragma unroll
        for (int l = 0; l < 4; ++l) {
            int idx = l * 256 + t;
            int p = idx >> 3, dc = (idx & 7) * 8;
            *(bf16x8*)(KV + p * 72 + dc) =
                *(const bf16x8*)(K + ((size_t)(bs_off + jb + p)) * 3072 + dc);
        }
        __syncthreads();

        f32x4 s_acc[2][8] = {};
#pragma unroll
        for (int ks = 0; ks < 2; ++ks) {
            bf16x8 bk8[8];
#pragma unroll
            for (int tj = 0; tj < 8; ++tj)
                bk8[tj] = *(bf16x8*)(KV + (tj * 16 + l16) * 72 + ks * 32 + quad * 8);
#pragma unroll
            for (int ti = 0; ti < 2; ++ti)
#pragma unroll
                for (int tj = 0; tj < 8; ++tj)
                    s_acc[ti][tj] = mfma16(aq[ti][ks], bk8[tj], s_acc[ti][tj]);
        }

        float negj[8]; int jcol[8];
#pragma unroll
        for (int tj = 0; tj < 8; ++tj) {
            jcol[tj] = jb + tj * 16 + l16;
            negj[tj] = (mask[bs_off + jcol[tj]] != 0) ? NEGF : 0.f;
        }
        float tmax[2][4];
#pragma unroll
        for (int ti = 0; ti < 2; ++ti)
#pragma unroll
            for (int r = 0; r < 4; ++r) tmax[ti][r] = NEGF;
#pragma unroll
        for (int ti = 0; ti < 2; ++ti) {
            int irow_base = q0 + wave * 32 + ti * 16 + quad * 4;
#pragma unroll
            for (int tj = 0; tj < 8; ++tj)
#pragma unroll
                for (int r = 0; r < 4; ++r) {
                    int dj = jcol[tj] - (irow_base + r);
                    float sc = (dj >= -128 && dj <= 128) ? (s_acc[ti][tj][r] + negj[tj]) : NEGF;
                    s_acc[ti][tj][r] = sc;
                    tmax[ti][r] = fmaxf(tmax[ti][r], sc);
                }
        }
#pragma unroll
        for (int ti = 0; ti < 2; ++ti)
#pragma unroll
            for (int r = 0; r < 4; ++r)
#pragma unroll
                for (int dsh = 1; dsh < 16; dsh <<= 1)
                    tmax[ti][r] = fmaxf(tmax[ti][r], __shfl_xor(tmax[ti][r], dsh));

        float alpha[2][4], lsum[2][4];
#pragma unroll
        for (int ti = 0; ti < 2; ++ti)
#pragma unroll
            for (int r = 0; r < 4; ++r) {
                float mnew = fmaxf(m_run[ti][r], tmax[ti][r]);
                alpha[ti][r] = safe_exp(m_run[ti][r] - mnew);
                m_run[ti][r] = mnew;
                lsum[ti][r] = 0.f;
            }
#pragma unroll
        for (int ti = 0; ti < 2; ++ti)
#pragma unroll
            for (int tj = 0; tj < 8; ++tj)
#pragma unroll
                for (int r = 0; r < 4; ++r) {
                    float p = safe_exp(s_acc[ti][tj][r] - m_run[ti][r]);
                    lsum[ti][r] += p;
                    PsQ[(wave * 32 + ti * 16 + quad * 4 + r) * 136 + tj * 16 + l16] = f2b(p);
                }
#pragma unroll
        for (int ti = 0; ti < 2; ++ti)
#pragma unroll
            for (int r = 0; r < 4; ++r) {
#pragma unroll
                for (int dsh = 1; dsh < 16; dsh <<= 1) lsum[ti][r] += __shfl_xor(lsum[ti][r], dsh);
                l_run[ti][r] = l_run[ti][r] * alpha[ti][r] + lsum[ti][r];
            }
#pragma unroll
        for (int ti = 0; ti < 2; ++ti)
#pragma unroll
            for (int dj = 0; dj < 4; ++dj)
#pragma unroll
                for (int r = 0; r < 4; ++r) o_acc[ti][dj][r] *= alpha[ti][r];

        __syncthreads();
#pragma unroll
        for (int l = 0; l < 4; ++l) {
            int idx = l * 256 + t;
            int d = idx >> 4, kc = (idx & 15) * 8;
            *(bf16x8*)(KV + d * 136 + kc) =
                *(const bf16x8*)(Vt + ((size_t)(b * 16 + h) * 64 + d) * 2048 + jb + kc);
        }
        __syncthreads();
#pragma unroll
        for (int ks = 0; ks < 4; ++ks) {
            bf16x8 ap[2], bv8[4];
#pragma unroll
            for (int ti = 0; ti < 2; ++ti)
                ap[ti] = *(bf16x8*)(PsQ + (wave * 32 + ti * 16 + l16) * 136 + ks * 32 + quad * 8);
#pragma unroll
            for (int dj = 0; dj < 4; ++dj)
                bv8[dj] = *(bf16x8*)(KV + (dj * 16 + l16) * 136 + ks * 32 + quad * 8);
#pragma unroll
            for (int ti = 0; ti < 2; ++ti)
#pragma unroll
                for (int dj = 0; dj < 4; ++dj)
                    o_acc[ti][dj] = mfma16(ap[ti], bv8[dj], o_acc[ti][dj]);
        }
    }

#pragma unroll
    for (int ti = 0; ti < 2; ++ti) {
        int irow_base = q0 + wave * 32 + ti * 16 + quad * 4;
#pragma unroll
        for (int r = 0; r < 4; ++r) {
            int i = irow_base + r;
            float m2 = fmaxf(m_run[ti][r], s_g[ti][r]);
            float pg = safe_exp(s_g[ti][r] - m2);
            float al = safe_exp(m_run[ti][r] - m2);
            float l2 = l_run[ti][r] * al + pg;
            float invl = 1.f / fmaxf(l2, 1e-30f);
            float qm = (mask[bs_off + i] > 0) ? 0.f : 1.f;
#pragma unroll
            for (int dj = 0; dj < 4; ++dj) {
                int d = dj * 16 + l16;
                float val = (o_acc[ti][dj][r] * al + pg * gvf[d]) * invl * qm;
                attn[((size_t)(bs_off + i)) * 1024 + h * 64 + d] = f2b(val);
            }
        }
    }
}

// ---------------------------------------------------------------------------
// y = LN(x + attn) * g + b ; writes bf16 (GEMM input) AND fp32 (residual).
// ---------------------------------------------------------------------------
__global__ __launch_bounds__(256) void resid_ln(
    const float* __restrict__ x, const short* __restrict__ attn,
    const float* __restrict__ g, const float* __restrict__ be,
    short* __restrict__ yb, float* __restrict__ yf)
{
    int row = blockIdx.x, t = threadIdx.x;
    int lane = t & 63, wave = t >> 6;
    const size_t base = (size_t)row * 1024;
    float v[4]; float s = 0.f, s2 = 0.f;
#pragma unroll
    for (int i = 0; i < 4; ++i) {
        int c = i * 256 + t;
        float val = x[base + c] + b2f(attn[base + c]);
        v[i] = val; s += val; s2 += val * val;
    }
#pragma unroll
    for (int off = 32; off > 0; off >>= 1) { s += __shfl_xor(s, off); s2 += __shfl_xor(s2, off); }
    __shared__ float red[8];
    if (lane == 0) { red[wave] = s; red[4 + wave] = s2; }
    __syncthreads();
    s  = red[0] + red[1] + red[2] + red[3];
    s2 = red[4] + red[5] + red[6] + red[7];
    float mu  = s * (1.f / 1024.f);
    float var = s2 * (1.f / 1024.f) - mu * mu;
    float inv = rsqrtf(fmaxf(var, 0.f) + 1e-5f);
#pragma unroll
    for (int i = 0; i < 4; ++i) {
        int c = i * 256 + t;
        float o = (v[i] - mu) * inv * g[c] + be[c];
        yb[base + c] = f2b(o);
        yf[base + c] = o;
    }
}

// ---------------------------------------------------------------------------
// workspace layout, units = bf16 elements (2 B). total 47M units = 94 MB.
// ---------------------------------------------------------------------------
static constexpr size_t MEG      = 1048576;
static constexpr size_t OFF_WQKV = 0;            // 3M  (3072x1024 bf16)
static constexpr size_t OFF_W1T  = 3 * MEG;      // 4M
static constexpr size_t OFF_W2T  = 7 * MEG;      // 4M
static constexpr size_t OFF_XB   = 11 * MEG;     // 4M
static constexpr size_t OFF_QKV  = 15 * MEG;     // 12M (4096x3072 bf16; V third unused)
static constexpr size_t OFF_VT   = 27 * MEG;     // 4M
static constexpr size_t OFF_ATT  = 31 * MEG;     // 4M
static constexpr size_t OFF_YN   = 35 * MEG;     // 4M (bf16)
static constexpr size_t OFF_YF   = 39 * MEG;     // 8M units = 4M fp32
static constexpr size_t OFF_H    = OFF_QKV;      // 16M, aliases QKV+VT (dead)

extern "C" void kernel_launch(void* const* d_in, const int* in_sizes, int n_in,
                              void* d_out, int out_size, void* d_ws, size_t ws_size,
                              hipStream_t stream) {
    (void)in_sizes; (void)n_in; (void)out_size; (void)ws_size;
    const float* x    = (const float*)d_in[0];
    const int*   mask = (const int*)  d_in[1];
    const float* wq   = (const float*)d_in[2];
    const float* bq   = (const float*)d_in[3];
    const float* wk   = (const float*)d_in[4];
    const float* bk   = (const float*)d_in[5];
    const float* wv   = (const float*)d_in[6];
    const float* bv   = (const float*)d_in[7];
    // d_in[8..13] (global-query branch) are provably dead for the output
    const float* lng  = (const float*)d_in[14];
    const float* lnb  = (const float*)d_in[15];
    const float* w1   = (const float*)d_in[16];
    const float* b1   = (const float*)d_in[17];
    const float* w2   = (const float*)d_in[18];
    const float* b2   = (const float*)d_in[19];
    short* ws  = (short*)d_ws;
    float* out = (float*)d_out;

    prep<<<15360, 256, 0, stream>>>(wq, wk, wv, w1, w2, x,
                                    ws + OFF_WQKV, ws + OFF_W1T,
                                    ws + OFF_W2T, ws + OFF_XB);

    gemm_qkv<<<dim3(32, 24), 256, 0, stream>>>(ws + OFF_XB, ws + OFF_WQKV,
                                               bq, bk, bv,
                                               ws + OFF_QKV, ws + OFF_VT);

    attn_kernel<<<512, 256, 53760, stream>>>(ws + OFF_QKV, ws + OFF_VT,
                                             mask, bk, bv, ws + OFF_ATT);

    resid_ln<<<4096, 256, 0, stream>>>(x, ws + OFF_ATT, lng, lnb,
                                       ws + OFF_YN, (float*)(ws + OFF_YF));

    gemm_gelu<<<dim3(32, 32), 256, 0, stream>>>(ws + OFF_YN, ws + OFF_W1T,
                                                b1, ws + OFF_H);

    gemm_out64<<<dim3(64, 16), 256, 0, stream>>>(ws + OFF_H, ws + OFF_W2T,
                                                 b2, (const float*)(ws + OFF_YF),
                                                 out, 4096, 1024, 4096);
}